// Round 19
// baseline (87.942 us; speedup 1.0000x reference)
//
#include <hip/hip_runtime.h>

typedef __attribute__((ext_vector_type(8))) short short8;
typedef __attribute__((ext_vector_type(8))) unsigned short ushort8;
typedef __attribute__((ext_vector_type(4))) unsigned short us4;
typedef __attribute__((ext_vector_type(4))) float f32x4;
typedef unsigned int u32;
typedef unsigned short u16;

#define AS_GLOBAL(p) ((const __attribute__((address_space(1))) u32*)(p))
#define AS_LDS(p) ((__attribute__((address_space(3))) u32*)(p))

#define NB 8192
#define ND 512
#define NH 128

// workspace byte offsets
#define OFF_XPK    0u          // [512 rowblk][16 kb][64 lane][8] bf16
#define OFF_W1PK   8388608u    // [32 pair][16 kb][8 nb][64][8] bf16 (= elem 4194304 from xpk)
#define OFF_W2PK   12582912u   // [32 pair][4 kb][4 nb][64][8] bf16
#define OFF_RW1PT  13107200u   // [2][64][512] bf16
#define OFF_RB1P   13238272u   // [2][64] f32
#define OFF_PBIAS  13238784u   // [32][8][128] f32
#define OFF_B1P    13369856u   // [32][128] f32
#define OFF_RWT    13402112u   // [32][8192] f32

__device__ __forceinline__ u16 f2bf(float f) {
  union { float f; u32 u; } v; v.f = f;
  return (u16)((v.u + 0x7FFFu + ((v.u >> 16) & 1u)) >> 16);
}

// ================= K_A: fused prep =================
// [0,512) cvt_x (LDS-bounce, coalesced) | [512,768) fold W1 (coalesced frag writes)
// [768,800) W2 | [800,802) router fold | 802 zero d_out
__global__ __launch_bounds__(256) void k_prep_all(
    const float* __restrict__ x, u16* __restrict__ xpk,
    const float* __restrict__ eg, const float* __restrict__ ebb,
    const float* __restrict__ em, const float* __restrict__ ev,
    const float* __restrict__ eW1, u16* __restrict__ w1pk, float* __restrict__ pbias,
    const float* __restrict__ eW2, u16* __restrict__ w2pk,
    const float* __restrict__ rbn_g, const float* __restrict__ rbn_b,
    const float* __restrict__ rbn_m, const float* __restrict__ rbn_v,
    const float* __restrict__ rW1, const float* __restrict__ rb1,
    u16* __restrict__ rw1pt, float* __restrict__ rb1p,
    float* __restrict__ out)
{
  __shared__ __align__(16) unsigned char sh[18432];
  const int blk = blockIdx.x, t = threadIdx.x;
  if (blk < 512) {
    // cvt_x: rowblock rb = blk (16 rows x 512 cols = 8192 floats)
    u16* tile = (u16*)sh;                    // [16][512] bf16, XOR-swizzled
    const float* src = x + (size_t)blk * 16 * ND;
#pragma unroll
    for (int j = 0; j < 8; ++j) {            // 8 * 256 thr * 4 floats = 8192
      int g = (j * 256 + t) * 4;             // float idx within block
      float4 v = *(const float4*)(src + g);
      int row = g >> 9, col = g & 511;       // col multiple of 4
      u32 byteoff = (u32)row * 1024 + (((u32)col * 2) ^ ((u32)(row & 7) << 4));
      us4 r4;
      r4[0] = f2bf(v.x); r4[1] = f2bf(v.y); r4[2] = f2bf(v.z); r4[3] = f2bf(v.w);
      *(us4*)((unsigned char*)tile + byteoff) = r4;   // 8B aligned
    }
    __syncthreads();
    // each wave writes 4 fragments as contiguous 1KB bursts
    const int lane = t & 63, wv = t >> 6;
    const int lr = lane & 15, q = lane >> 4;
#pragma unroll
    for (int jk = 0; jk < 4; ++jk) {
      int kb = wv * 4 + jk;
      u32 byteoff = (u32)lr * 1024 + (((u32)(kb * 64 + q * 16)) ^ ((u32)(lr & 7) << 4));
      ushort8 r = *(const ushort8*)((unsigned char*)tile + byteoff);
      *(ushort8*)(xpk + ((u32)(blk * 16 + kb) * 64 + lane) * 8) = r;
    }
  } else if (blk < 768) {
    // fold W1: pair/dc chunk; padded tile [64][132] u16; coalesced frag writes
    float* sa = (float*)sh;                      // [64]  @0
    float* sc = sa + 64;                         // [64]  @256
    u16* tile = (u16*)(sh + 512);                // [64][132] u16 (16896B)
    float* pb2 = (float*)(sh + 512 + 16896);     // [2][128] f32 (1024B) -> 18432
    const int pair = (blk - 512) >> 3, dc = (blk - 512) & 7;
    const int d0 = dc * 64;
    if (t < 64) {
      int d = pair * ND + d0 + t;
      float a = eg[d] * rsqrtf(ev[d] + 1e-5f);
      sa[t] = a;
      sc[t] = ebb[d] - em[d] * a;
    }
    __syncthreads();
    const int h = t & 127, pr = t >> 7;
    float acc = 0.f;
    const float* src = eW1 + (size_t)pair * ND * NH + (size_t)d0 * NH;
#pragma unroll
    for (int i = 0; i < 32; ++i) {
      int dl = i * 2 + pr;
      float w = src[dl * NH + h];
      tile[dl * 132 + h] = f2bf(w * sa[dl]);
      acc += w * sc[dl];
    }
    pb2[pr * 128 + h] = acc;
    __syncthreads();
    {
      // 16 fragments (kbl 0..1 x nb 0..7); wave wv writes f = wv*4..+3 as 1KB bursts
      const int lane = t & 63, wv = t >> 6;
      const int lr = lane & 15, q = lane >> 4;
#pragma unroll
      for (int ff = 0; ff < 4; ++ff) {
        int f = wv * 4 + ff;
        int kbl = f >> 3, nb = f & 7;
        ushort8 r;
#pragma unroll
        for (int j = 0; j < 8; ++j)
          r[j] = tile[(kbl * 32 + q * 8 + j) * 132 + nb * 16 + lr];
        *(ushort8*)(w1pk + ((u32)((pair * 16 + dc * 2 + kbl) * 8 + nb)) * 512
                    + (u32)lane * 8) = r;
      }
    }
    if (t < 128) pbias[(u32)(pair * 8 + dc) * 128 + t] = pb2[t] + pb2[128 + t];
  } else if (blk < 800) {
    const int pair = blk - 768;
    const float* w2 = eW2 + (size_t)pair * NH * 64;
    int n = t & 63, kk = t >> 6;
    for (int k = kk * 32; k < kk * 32 + 32; ++k) {
      u32 dst = ((u32)((pair * 4 + (k >> 5)) * 4 + (n >> 4))) * 512
              + (((k >> 3) & 3) * 16 + (n & 15)) * 8 + (k & 7);
      w2pk[dst] = f2bf(w2[k * 64 + n]);
    }
  } else if (blk < 802) {
    const int c = blk - 800;
    int n = t >> 2, q = t & 3;
    const float* g  = rbn_g + c * ND;
    const float* b  = rbn_b + c * ND;
    const float* m  = rbn_m + c * ND;
    const float* vv = rbn_v + c * ND;
    const float* w1 = rW1 + (size_t)c * ND * 64;
    float acc = 0.f;
    for (int d = q * 128; d < q * 128 + 128; ++d) {
      float a  = g[d] * rsqrtf(vv[d] + 1e-5f);
      float cc = b[d] - m[d] * a;
      float w  = w1[d * 64 + n];
      rw1pt[((u32)c * 64 + n) * ND + d] = f2bf(a * w);
      acc += cc * w;
    }
    acc += __shfl_xor(acc, 1, 64);
    acc += __shfl_xor(acc, 2, 64);
    if (q == 0) rb1p[c * 64 + n] = rb1[c * 64 + n] + acc;
  } else {
    float4 z; z.x = 0.f; z.y = 0.f; z.z = 0.f; z.w = 0.f;
    float4* o4 = (float4*)out;
#pragma unroll
    for (int j = 0; j < 8; ++j) o4[t * 8 + j] = z;
  }
}

// ================= K_R: router (0..255) + b1p reduce (256..287) =================
__global__ __launch_bounds__(256) void k_router(
    const u16* __restrict__ xpk, const u16* __restrict__ rw1pt,
    const float* __restrict__ rb1p, const float* __restrict__ rW2,
    const float* __restrict__ rb2, const float* __restrict__ rW3,
    const float* __restrict__ rb3, float* __restrict__ rwT,
    const float* __restrict__ pbias, const float* __restrict__ eb1,
    float* __restrict__ b1p)
{
  __shared__ float h1l[64][65];
  __shared__ float h2l[64][33];
  __shared__ float w2s[2048];
  __shared__ float w3s[512];
  const int tid = threadIdx.x;
  if (blockIdx.x >= 256) {
    const int pair = blockIdx.x - 256;
    if (tid < 128) {
      float s = eb1[pair * NH + tid];
#pragma unroll
      for (int dc = 0; dc < 8; ++dc) s += pbias[(u32)(pair * 8 + dc) * 128 + tid];
      b1p[pair * NH + tid] = s;
    }
    return;
  }
  const int lane = tid & 63;
  const int wv = tid >> 6;
  const int q = lane >> 4;
  const int lr = lane & 15;
  const int c = blockIdx.x >> 7;
  const int r0 = (blockIdx.x & 127) * 64;
  {
    const float* W2 = rW2 + c * 2048;
    *(float4*)(w2s + tid * 8)     = *(const float4*)(W2 + tid * 8);
    *(float4*)(w2s + tid * 8 + 4) = *(const float4*)(W2 + tid * 8 + 4);
    if (tid < 128)
      *(float4*)(w3s + tid * 4) = *(const float4*)(rW3 + c * 512 + tid * 4);
  }
  f32x4 acc[4] = {};
  const u16* xfr   = xpk + ((u32)((r0 >> 4) + wv) * 16) * 512 + (u32)lane * 8;
  const u16* wbase = rw1pt + ((u32)c * 64 << 9);
  for (int kb = 0; kb < 16; ++kb) {
    short8 a = *(const short8*)(xfr + kb * 512);
#pragma unroll
    for (int u = 0; u < 4; ++u) {
      short8 b = *(const short8*)(wbase + (((u32)(u * 16 + lr)) << 9) + kb * 32 + q * 8);
      acc[u] = __builtin_amdgcn_mfma_f32_16x16x32_bf16(a, b, acc[u], 0, 0, 0);
    }
  }
#pragma unroll
  for (int u = 0; u < 4; ++u) {
    int n = u * 16 + lr;
    float bias = rb1p[c * 64 + n];
#pragma unroll
    for (int i = 0; i < 4; ++i) {
      float v = acc[u][i] + bias;
      h1l[wv * 16 + q * 4 + i][n] = v > 0.f ? v : 0.f;
    }
  }
  __syncthreads();
  {
    int row = tid >> 2, part = (tid & 3) * 8;
    float hv[8];
#pragma unroll
    for (int j = 0; j < 8; ++j) hv[j] = rb2[c * 32 + part + j];
#pragma unroll
    for (int k = 0; k < 64; ++k) {
      float hk = h1l[row][k];
#pragma unroll
      for (int j = 0; j < 8; ++j) hv[j] += hk * w2s[k * 32 + part + j];
    }
#pragma unroll
    for (int j = 0; j < 8; ++j) h2l[row][part + j] = hv[j] > 0.f ? hv[j] : 0.f;
  }
  __syncthreads();
  {
    int row = tid >> 2, e0 = (tid & 3) * 4;
    float lg[4];
#pragma unroll
    for (int e = 0; e < 4; ++e) {
      float a3 = rb3[c * 16 + e0 + e];
#pragma unroll
      for (int k = 0; k < 32; ++k) a3 += h2l[row][k] * w3s[k * 16 + e0 + e];
      lg[e] = a3;
    }
    float mx = fmaxf(fmaxf(lg[0], lg[1]), fmaxf(lg[2], lg[3]));
    mx = fmaxf(mx, __shfl_xor(mx, 1, 64));
    mx = fmaxf(mx, __shfl_xor(mx, 2, 64));
    float sm = 0.f;
#pragma unroll
    for (int e = 0; e < 4; ++e) { lg[e] = __expf(lg[e] - mx); sm += lg[e]; }
    sm += __shfl_xor(sm, 1, 64);
    sm += __shfl_xor(sm, 2, 64);
    float inv = 1.f / sm;
#pragma unroll
    for (int e = 0; e < 4; ++e)
      rwT[(u32)(c * 16 + e0 + e) * NB + r0 + row] = lg[e] * inv;
  }
}

// ================= K_E: experts (R14's measured body, unchanged) =================
__global__ __launch_bounds__(256, 2) void k_expert(
    const u16* __restrict__ xpk, const float* __restrict__ b1p,
    const u16* __restrict__ w2pk,
    const float* __restrict__ eb2, const float* __restrict__ eW3,
    const float* __restrict__ eb3, const float* __restrict__ rwT,
    const float* __restrict__ bw, float* __restrict__ out)
{
  extern __shared__ __align__(16) unsigned char smem[];  // 73728 = 3 x 24KB
  const int tid = threadIdx.x;
  const int lane = tid & 63;
  const int wv = tid >> 6;            // 0..3
  const int q = lane >> 4, lr = lane & 15;
  const int wr = wv >> 1;             // row half
  const int p  = wv & 1;              // pair owned in GEMM1
  const int xcd  = blockIdx.x & 7;
  const int slot = blockIdx.x >> 3;   // 0..127
  const int pt   = xcd * 2 + (slot & 1);
  const int bt   = slot >> 1;         // 0..63
  const int pr0  = pt * 2;
  const int r0   = bt * 128;
  const u32 lane16 = (u32)lane * 16;

  u32 soff[6], sstep[6], slds[6];
#pragma unroll
  for (int j = 0; j < 6; ++j) {
    int f = wv * 6 + j;
    if (f < 8) {
      soff[j]  = ((u32)(bt * 8 + f) * 16) * 512 + (u32)lane * 8;
      sstep[j] = 512;
      slds[j]  = (u32)f * 1024;
    } else {
      int g = f - 8;
      soff[j]  = 4194304u + ((u32)(pr0 + (g >> 3)) * 128 + (g & 7)) * 512 + (u32)lane * 8;
      sstep[j] = 4096;
      slds[j]  = 8192 + (u32)g * 1024;
    }
  }

#define STAGE(BUF, KB) do { \
  _Pragma("unroll") for (int j_ = 0; j_ < 6; ++j_) \
    __builtin_amdgcn_global_load_lds( \
        AS_GLOBAL(xpk + soff[j_] + (u32)(KB) * sstep[j_]), \
        AS_LDS(smem + (BUF) + slds[j_]), 16, 0, 0); \
  } while (0)

  f32x4 acc[4][8] = {};

  STAGE(0u, 0);
  STAGE(24576u, 1);
  asm volatile("s_waitcnt vmcnt(6)" ::: "memory");
  __builtin_amdgcn_s_barrier();

#pragma unroll
  for (int kb = 0; kb < 16; ++kb) {
    const u32 BUF = (u32)(kb % 3) * 24576u;
    if (kb < 14) {
      STAGE((u32)((kb + 2) % 3) * 24576u, kb + 2);
      __builtin_amdgcn_sched_barrier(0);   // keep stage issues early
    }
    short8 a_[4], b_[8];
#pragma unroll
    for (int t = 0; t < 4; ++t)
      a_[t] = *(const short8*)(smem + BUF + (u32)(wr * 4 + t) * 1024 + lane16);
#pragma unroll
    for (int u = 0; u < 8; ++u)
      b_[u] = *(const short8*)(smem + BUF + 8192 + (u32)(p * 8 + u) * 1024 + lane16);
#pragma unroll
    for (int t = 0; t < 4; ++t)
#pragma unroll
      for (int u = 0; u < 8; ++u)
        acc[t][u] = __builtin_amdgcn_mfma_f32_16x16x32_bf16(a_[t], b_[u], acc[t][u], 0, 0, 0);
    if (kb < 14)       asm volatile("s_waitcnt vmcnt(6)" ::: "memory");
    else if (kb == 14) asm volatile("s_waitcnt vmcnt(0)" ::: "memory");
    if (kb < 15) __builtin_amdgcn_s_barrier();
  }
#undef STAGE

  __syncthreads();

  // ---- merged tail: h1 BOTH pairs -> smem[0..64K) fragment-packed ----
  {
    float b1w[8];
#pragma unroll
    for (int u = 0; u < 8; ++u) b1w[u] = b1p[(pr0 + p) * NH + u * 16 + lr];
#pragma unroll
    for (int t = 0; t < 4; ++t)
#pragma unroll
      for (int u = 0; u < 8; ++u) {
        const int rb = wr * 4 + t;
        const int kb2 = u >> 1;
        const int q2 = (u & 1) * 2 + (lr >> 3), j2 = lr & 7;
#pragma unroll
        for (int i = 0; i < 4; ++i) {
          float v = acc[t][u][i] + b1w[u];
          v = v > 0.f ? v : 0.f;
          u32 byteoff = ((u32)(((p * 8 + rb) * 4 + kb2) * 64 + q2 * 16 + q * 4 + i)) * 16 + j2 * 2;
          *(u16*)(smem + byteoff) = f2bf(v);
        }
      }
  }
  __syncthreads();

  // GEMM2 single sweep: wave owns rows wv*32..+31 for BOTH pairs
  f32x4 acc2[2][2][4] = {};
#pragma unroll
  for (int pl = 0; pl < 2; ++pl)
#pragma unroll
    for (int kk = 0; kk < 4; ++kk) {
      short8 a2[2], b2v[4];
#pragma unroll
      for (int t2 = 0; t2 < 2; ++t2)
        a2[t2] = *(const short8*)(smem + (u32)(((pl * 8 + wv * 2 + t2) * 4 + kk)) * 1024 + lane16);
#pragma unroll
      for (int u2 = 0; u2 < 4; ++u2)
        b2v[u2] = *(const short8*)(w2pk + ((u32)(((pr0 + pl) * 4 + kk) * 4 + u2)) * 512 + (u32)lane * 8);
#pragma unroll
      for (int t2 = 0; t2 < 2; ++t2)
#pragma unroll
        for (int u2 = 0; u2 < 4; ++u2)
          acc2[pl][t2][u2] = __builtin_amdgcn_mfma_f32_16x16x32_bf16(a2[t2], b2v[u2], acc2[pl][t2][u2], 0, 0, 0);
    }

  // epilogue: s = sigmoid(relu(h2+b2).W3+b3); out += bw_c * rw * s (atomic)
#pragma unroll
  for (int pl = 0; pl < 2; ++pl) {
    const int pairG = pr0 + pl;
    float bb2[4], bw3v[4];
#pragma unroll
    for (int u2 = 0; u2 < 4; ++u2) {
      bb2[u2]  = eb2[pairG * 64 + u2 * 16 + lr];
      bw3v[u2] = eW3[pairG * 64 + u2 * 16 + lr];
    }
    float b3 = eb3[pairG];
    float bwc = bw[pairG >> 4];
#pragma unroll
    for (int t2 = 0; t2 < 2; ++t2) {
      float pp[4] = {0.f, 0.f, 0.f, 0.f};
#pragma unroll
      for (int u2 = 0; u2 < 4; ++u2)
#pragma unroll
        for (int i = 0; i < 4; ++i) {
          float h = acc2[pl][t2][u2][i] + bb2[u2];
          h = h > 0.f ? h : 0.f;
          pp[i] += h * bw3v[u2];
        }
#pragma unroll
      for (int m = 1; m < 16; m <<= 1)
#pragma unroll
        for (int i = 0; i < 4; ++i) pp[i] += __shfl_xor(pp[i], m, 64);
      if (lr == 0) {
#pragma unroll
        for (int i = 0; i < 4; ++i) {
          int row = wv * 32 + t2 * 16 + q * 4 + i;
          float z = pp[i] + b3;
          float s = 1.f / (1.f + __expf(-z));
          float rw = rwT[(u32)pairG * NB + r0 + row];
          atomicAdd(out + r0 + row, bwc * rw * s);
        }
      }
    }
  }
}

extern "C" void kernel_launch(void* const* d_in, const int* in_sizes, int n_in,
                              void* d_out, int out_size, void* d_ws, size_t ws_size,
                              hipStream_t stream) {
  const float* x     = (const float*)d_in[0];
  const float* rbn_g = (const float*)d_in[1];
  const float* rbn_b = (const float*)d_in[2];
  const float* rbn_m = (const float*)d_in[3];
  const float* rbn_v = (const float*)d_in[4];
  const float* rW1   = (const float*)d_in[5];
  const float* rb1   = (const float*)d_in[6];
  const float* rW2   = (const float*)d_in[7];
  const float* rb2   = (const float*)d_in[8];
  const float* rW3   = (const float*)d_in[9];
  const float* rb3   = (const float*)d_in[10];
  const float* ebn_g = (const float*)d_in[11];
  const float* ebn_b = (const float*)d_in[12];
  const float* ebn_m = (const float*)d_in[13];
  const float* ebn_v = (const float*)d_in[14];
  const float* eW1   = (const float*)d_in[15];
  const float* eb1   = (const float*)d_in[16];
  const float* eW2   = (const float*)d_in[17];
  const float* eb2   = (const float*)d_in[18];
  const float* eW3   = (const float*)d_in[19];
  const float* eb3   = (const float*)d_in[20];
  const float* bw    = (const float*)d_in[21];

  char* ws = (char*)d_ws;
  u16*   xpk   = (u16*)(ws + OFF_XPK);
  u16*   w1pk  = (u16*)(ws + OFF_W1PK);
  u16*   w2pk  = (u16*)(ws + OFF_W2PK);
  u16*   rw1pt = (u16*)(ws + OFF_RW1PT);
  float* rb1p  = (float*)(ws + OFF_RB1P);
  float* pbias = (float*)(ws + OFF_PBIAS);
  float* b1p   = (float*)(ws + OFF_B1P);
  float* rwT   = (float*)(ws + OFF_RWT);
  float* outf  = (float*)d_out;

  k_prep_all<<<dim3(803), dim3(256), 0, stream>>>(
      x, xpk, ebn_g, ebn_b, ebn_m, ebn_v, eW1, w1pk, pbias, eW2, w2pk,
      rbn_g, rbn_b, rbn_m, rbn_v, rW1, rb1, rw1pt, rb1p, outf);
  k_router<<<dim3(288), dim3(256), 0, stream>>>(
      xpk, rw1pt, rb1p, rW2, rb2, rW3, rb3, rwT, pbias, eb1, b1p);
  k_expert<<<dim3(1024), dim3(256), 73728, stream>>>(
      xpk, b1p, w2pk, eb2, eW3, eb3, rwT, bw, outf);
}

// Round 20
// 73.950 us; speedup vs baseline: 1.1892x; 1.1892x over previous
//
#include <hip/hip_runtime.h>

typedef __attribute__((ext_vector_type(8))) short short8;
typedef __attribute__((ext_vector_type(8))) unsigned short ushort8;
typedef __attribute__((ext_vector_type(4))) unsigned short us4;
typedef __attribute__((ext_vector_type(4))) float f32x4;
typedef unsigned int u32;
typedef unsigned short u16;

#define AS_GLOBAL(p) ((const __attribute__((address_space(1))) u32*)(p))
#define AS_LDS(p) ((__attribute__((address_space(3))) u32*)(p))

#define NB 8192
#define ND 512
#define NH 128

// workspace byte offsets
#define OFF_XPK    0u          // [512 rowblk][16 kb][64 lane][8] bf16
#define OFF_W1PK   8388608u    // [32 pair][16 kb][8 nb][64][8] bf16 (= elem 4194304 from xpk)
#define OFF_W2PK   12582912u   // [32 pair][4 kb][4 nb][64][8] bf16
#define OFF_RW1PT  13107200u   // [2][64][512] bf16
#define OFF_PBIAS  13238784u   // [32][8][128] f32
#define OFF_B1P    13369856u   // [32][128] f32
#define OFF_RWT    13402112u   // [32][8192] f32 (ends 14450688)
#define OFF_RPB    14450688u   // [2][16][64] f32 router-bias partials (8KB)

__device__ __forceinline__ u16 f2bf(float f) {
  union { float f; u32 u; } v; v.f = f;
  return (u16)((v.u + 0x7FFFu + ((v.u >> 16) & 1u)) >> 16);
}

// ================= K_A: fused prep =================
// [0,512) cvt_x | [512,768) fold W1 | [768,800) W2 | [800,832) router fold (32 blk)
// | 832 zero d_out
__global__ __launch_bounds__(256) void k_prep_all(
    const float* __restrict__ x, u16* __restrict__ xpk,
    const float* __restrict__ eg, const float* __restrict__ ebb,
    const float* __restrict__ em, const float* __restrict__ ev,
    const float* __restrict__ eW1, u16* __restrict__ w1pk, float* __restrict__ pbias,
    const float* __restrict__ eW2, u16* __restrict__ w2pk,
    const float* __restrict__ rbn_g, const float* __restrict__ rbn_b,
    const float* __restrict__ rbn_m, const float* __restrict__ rbn_v,
    const float* __restrict__ rW1,
    u16* __restrict__ rw1pt, float* __restrict__ rpb,
    float* __restrict__ out)
{
  __shared__ __align__(16) unsigned char sh[18432];
  const int blk = blockIdx.x, t = threadIdx.x;
  if (blk < 512) {
    // cvt_x: rowblock rb = blk (16 rows x 512 cols = 8192 floats)
    u16* tile = (u16*)sh;                    // [16][512] bf16, XOR-swizzled
    const float* src = x + (size_t)blk * 16 * ND;
#pragma unroll
    for (int j = 0; j < 8; ++j) {
      int g = (j * 256 + t) * 4;
      float4 v = *(const float4*)(src + g);
      int row = g >> 9, col = g & 511;
      u32 byteoff = (u32)row * 1024 + (((u32)col * 2) ^ ((u32)(row & 7) << 4));
      us4 r4;
      r4[0] = f2bf(v.x); r4[1] = f2bf(v.y); r4[2] = f2bf(v.z); r4[3] = f2bf(v.w);
      *(us4*)((unsigned char*)tile + byteoff) = r4;
    }
    __syncthreads();
    const int lane = t & 63, wv = t >> 6;
    const int lr = lane & 15, q = lane >> 4;
#pragma unroll
    for (int jk = 0; jk < 4; ++jk) {
      int kb = wv * 4 + jk;
      u32 byteoff = (u32)lr * 1024 + (((u32)(kb * 64 + q * 16)) ^ ((u32)(lr & 7) << 4));
      ushort8 r = *(const ushort8*)((unsigned char*)tile + byteoff);
      *(ushort8*)(xpk + ((u32)(blk * 16 + kb) * 64 + lane) * 8) = r;
    }
  } else if (blk < 768) {
    // fold W1: padded tile [64][132] u16; coalesced frag writes
    float* sa = (float*)sh;
    float* sc = sa + 64;
    u16* tile = (u16*)(sh + 512);                // [64][132]
    float* pb2 = (float*)(sh + 512 + 16896);     // [2][128]
    const int pair = (blk - 512) >> 3, dc = (blk - 512) & 7;
    const int d0 = dc * 64;
    if (t < 64) {
      int d = pair * ND + d0 + t;
      float a = eg[d] * rsqrtf(ev[d] + 1e-5f);
      sa[t] = a;
      sc[t] = ebb[d] - em[d] * a;
    }
    __syncthreads();
    const int h = t & 127, pr = t >> 7;
    float acc = 0.f;
    const float* src = eW1 + (size_t)pair * ND * NH + (size_t)d0 * NH;
#pragma unroll
    for (int i = 0; i < 32; ++i) {
      int dl = i * 2 + pr;
      float w = src[dl * NH + h];
      tile[dl * 132 + h] = f2bf(w * sa[dl]);
      acc += w * sc[dl];
    }
    pb2[pr * 128 + h] = acc;
    __syncthreads();
    {
      const int lane = t & 63, wv = t >> 6;
      const int lr = lane & 15, q = lane >> 4;
#pragma unroll
      for (int ff = 0; ff < 4; ++ff) {
        int f = wv * 4 + ff;
        int kbl = f >> 3, nb = f & 7;
        ushort8 r;
#pragma unroll
        for (int j = 0; j < 8; ++j)
          r[j] = tile[(kbl * 32 + q * 8 + j) * 132 + nb * 16 + lr];
        *(ushort8*)(w1pk + ((u32)((pair * 16 + dc * 2 + kbl) * 8 + nb)) * 512
                    + (u32)lane * 8) = r;
      }
    }
    if (t < 128) pbias[(u32)(pair * 8 + dc) * 128 + t] = pb2[t] + pb2[128 + t];
  } else if (blk < 800) {
    const int pair = blk - 768;
    const float* w2 = eW2 + (size_t)pair * NH * 64;
    int n = t & 63, kk = t >> 6;
    for (int k = kk * 32; k < kk * 32 + 32; ++k) {
      u32 dst = ((u32)((pair * 4 + (k >> 5)) * 4 + (n >> 4))) * 512
              + (((k >> 3) & 3) * 16 + (n & 15)) * 8 + (k & 7);
      w2pk[dst] = f2bf(w2[k * 64 + n]);
    }
  } else if (blk < 832) {
    // router fold, parallelized: 32 blocks = 2 c x 16 d-chunks of 32
    float* red = (float*)sh;                    // [4][64]
    const int b = blk - 800, c = b >> 4, dc = b & 15;
    const int n = t & 63, dg = t >> 6;
    const int d0 = dc * 32 + dg * 8;
    const float* g  = rbn_g + c * ND;
    const float* bb = rbn_b + c * ND;
    const float* m  = rbn_m + c * ND;
    const float* vv = rbn_v + c * ND;
    const float* w1 = rW1 + (size_t)c * ND * 64;
    float acc = 0.f;
    ushort8 r;
#pragma unroll
    for (int j = 0; j < 8; ++j) {
      int d = d0 + j;
      float a  = g[d] * rsqrtf(vv[d] + 1e-5f);
      float cc = bb[d] - m[d] * a;
      float w  = w1[d * 64 + n];
      r[j] = f2bf(a * w);
      acc += cc * w;
    }
    *(ushort8*)(rw1pt + ((u32)(c * 64 + n)) * 512 + d0) = r;
    red[dg * 64 + n] = acc;
    __syncthreads();
    if (t < 64)
      rpb[(u32)(c * 16 + dc) * 64 + t] = red[t] + red[64 + t] + red[128 + t] + red[192 + t];
  } else {
    float4 z; z.x = 0.f; z.y = 0.f; z.z = 0.f; z.w = 0.f;
    float4* o4 = (float4*)out;
#pragma unroll
    for (int j = 0; j < 8; ++j) o4[t * 8 + j] = z;
  }
}

// ================= K_R: router (0..255) + b1p reduce (256..287) =================
__global__ __launch_bounds__(256) void k_router(
    const u16* __restrict__ xpk, const u16* __restrict__ rw1pt,
    const float* __restrict__ rb1, const float* __restrict__ rpb,
    const float* __restrict__ rW2,
    const float* __restrict__ rb2, const float* __restrict__ rW3,
    const float* __restrict__ rb3, float* __restrict__ rwT,
    const float* __restrict__ pbias, const float* __restrict__ eb1,
    float* __restrict__ b1p)
{
  __shared__ float h1l[64][65];
  __shared__ float h2l[64][33];
  __shared__ float w2s[2048];
  __shared__ float w3s[512];
  __shared__ float rb1s[64];
  const int tid = threadIdx.x;
  if (blockIdx.x >= 256) {
    const int pair = blockIdx.x - 256;
    if (tid < 128) {
      float s = eb1[pair * NH + tid];
#pragma unroll
      for (int dc = 0; dc < 8; ++dc) s += pbias[(u32)(pair * 8 + dc) * 128 + tid];
      b1p[pair * NH + tid] = s;
    }
    return;
  }
  const int lane = tid & 63;
  const int wv = tid >> 6;
  const int q = lane >> 4;
  const int lr = lane & 15;
  const int c = blockIdx.x >> 7;
  const int r0 = (blockIdx.x & 127) * 64;
  {
    const float* W2 = rW2 + c * 2048;
    *(float4*)(w2s + tid * 8)     = *(const float4*)(W2 + tid * 8);
    *(float4*)(w2s + tid * 8 + 4) = *(const float4*)(W2 + tid * 8 + 4);
    if (tid < 128)
      *(float4*)(w3s + tid * 4) = *(const float4*)(rW3 + c * 512 + tid * 4);
    if (tid < 64) {
      float s = rb1[c * 64 + tid];
#pragma unroll
      for (int k = 0; k < 16; ++k) s += rpb[(u32)(c * 16 + k) * 64 + tid];
      rb1s[tid] = s;
    }
  }
  __syncthreads();
  f32x4 acc[4] = {};
  const u16* xfr   = xpk + ((u32)((r0 >> 4) + wv) * 16) * 512 + (u32)lane * 8;
  const u16* wbase = rw1pt + ((u32)c * 64 << 9);
  for (int kb = 0; kb < 16; ++kb) {
    short8 a = *(const short8*)(xfr + kb * 512);
#pragma unroll
    for (int u = 0; u < 4; ++u) {
      short8 b = *(const short8*)(wbase + (((u32)(u * 16 + lr)) << 9) + kb * 32 + q * 8);
      acc[u] = __builtin_amdgcn_mfma_f32_16x16x32_bf16(a, b, acc[u], 0, 0, 0);
    }
  }
#pragma unroll
  for (int u = 0; u < 4; ++u) {
    int n = u * 16 + lr;
    float bias = rb1s[n];
#pragma unroll
    for (int i = 0; i < 4; ++i) {
      float v = acc[u][i] + bias;
      h1l[wv * 16 + q * 4 + i][n] = v > 0.f ? v : 0.f;
    }
  }
  __syncthreads();
  {
    int row = tid >> 2, part = (tid & 3) * 8;
    float hv[8];
#pragma unroll
    for (int j = 0; j < 8; ++j) hv[j] = rb2[c * 32 + part + j];
#pragma unroll
    for (int k = 0; k < 64; ++k) {
      float hk = h1l[row][k];
#pragma unroll
      for (int j = 0; j < 8; ++j) hv[j] += hk * w2s[k * 32 + part + j];
    }
#pragma unroll
    for (int j = 0; j < 8; ++j) h2l[row][part + j] = hv[j] > 0.f ? hv[j] : 0.f;
  }
  __syncthreads();
  {
    int row = tid >> 2, e0 = (tid & 3) * 4;
    float lg[4];
#pragma unroll
    for (int e = 0; e < 4; ++e) {
      float a3 = rb3[c * 16 + e0 + e];
#pragma unroll
      for (int k = 0; k < 32; ++k) a3 += h2l[row][k] * w3s[k * 16 + e0 + e];
      lg[e] = a3;
    }
    float mx = fmaxf(fmaxf(lg[0], lg[1]), fmaxf(lg[2], lg[3]));
    mx = fmaxf(mx, __shfl_xor(mx, 1, 64));
    mx = fmaxf(mx, __shfl_xor(mx, 2, 64));
    float sm = 0.f;
#pragma unroll
    for (int e = 0; e < 4; ++e) { lg[e] = __expf(lg[e] - mx); sm += lg[e]; }
    sm += __shfl_xor(sm, 1, 64);
    sm += __shfl_xor(sm, 2, 64);
    float inv = 1.f / sm;
#pragma unroll
    for (int e = 0; e < 4; ++e)
      rwT[(u32)(c * 16 + e0 + e) * NB + r0 + row] = lg[e] * inv;
  }
}

// ================= K_E: experts (R14's measured body, unchanged) =================
__global__ __launch_bounds__(256, 2) void k_expert(
    const u16* __restrict__ xpk, const float* __restrict__ b1p,
    const u16* __restrict__ w2pk,
    const float* __restrict__ eb2, const float* __restrict__ eW3,
    const float* __restrict__ eb3, const float* __restrict__ rwT,
    const float* __restrict__ bw, float* __restrict__ out)
{
  extern __shared__ __align__(16) unsigned char smem[];  // 73728 = 3 x 24KB
  const int tid = threadIdx.x;
  const int lane = tid & 63;
  const int wv = tid >> 6;            // 0..3
  const int q = lane >> 4, lr = lane & 15;
  const int wr = wv >> 1;             // row half
  const int p  = wv & 1;              // pair owned in GEMM1
  const int xcd  = blockIdx.x & 7;
  const int slot = blockIdx.x >> 3;   // 0..127
  const int pt   = xcd * 2 + (slot & 1);
  const int bt   = slot >> 1;         // 0..63
  const int pr0  = pt * 2;
  const int r0   = bt * 128;
  const u32 lane16 = (u32)lane * 16;

  u32 soff[6], sstep[6], slds[6];
#pragma unroll
  for (int j = 0; j < 6; ++j) {
    int f = wv * 6 + j;
    if (f < 8) {
      soff[j]  = ((u32)(bt * 8 + f) * 16) * 512 + (u32)lane * 8;
      sstep[j] = 512;
      slds[j]  = (u32)f * 1024;
    } else {
      int g = f - 8;
      soff[j]  = 4194304u + ((u32)(pr0 + (g >> 3)) * 128 + (g & 7)) * 512 + (u32)lane * 8;
      sstep[j] = 4096;
      slds[j]  = 8192 + (u32)g * 1024;
    }
  }

#define STAGE(BUF, KB) do { \
  _Pragma("unroll") for (int j_ = 0; j_ < 6; ++j_) \
    __builtin_amdgcn_global_load_lds( \
        AS_GLOBAL(xpk + soff[j_] + (u32)(KB) * sstep[j_]), \
        AS_LDS(smem + (BUF) + slds[j_]), 16, 0, 0); \
  } while (0)

  f32x4 acc[4][8] = {};

  STAGE(0u, 0);
  STAGE(24576u, 1);
  asm volatile("s_waitcnt vmcnt(6)" ::: "memory");
  __builtin_amdgcn_s_barrier();

#pragma unroll
  for (int kb = 0; kb < 16; ++kb) {
    const u32 BUF = (u32)(kb % 3) * 24576u;
    if (kb < 14) {
      STAGE((u32)((kb + 2) % 3) * 24576u, kb + 2);
      __builtin_amdgcn_sched_barrier(0);   // keep stage issues early
    }
    short8 a_[4], b_[8];
#pragma unroll
    for (int t = 0; t < 4; ++t)
      a_[t] = *(const short8*)(smem + BUF + (u32)(wr * 4 + t) * 1024 + lane16);
#pragma unroll
    for (int u = 0; u < 8; ++u)
      b_[u] = *(const short8*)(smem + BUF + 8192 + (u32)(p * 8 + u) * 1024 + lane16);
#pragma unroll
    for (int t = 0; t < 4; ++t)
#pragma unroll
      for (int u = 0; u < 8; ++u)
        acc[t][u] = __builtin_amdgcn_mfma_f32_16x16x32_bf16(a_[t], b_[u], acc[t][u], 0, 0, 0);
    if (kb < 14)       asm volatile("s_waitcnt vmcnt(6)" ::: "memory");
    else if (kb == 14) asm volatile("s_waitcnt vmcnt(0)" ::: "memory");
    if (kb < 15) __builtin_amdgcn_s_barrier();
  }
#undef STAGE

  __syncthreads();

  // ---- merged tail: h1 BOTH pairs -> smem[0..64K) fragment-packed ----
  {
    float b1w[8];
#pragma unroll
    for (int u = 0; u < 8; ++u) b1w[u] = b1p[(pr0 + p) * NH + u * 16 + lr];
#pragma unroll
    for (int t = 0; t < 4; ++t)
#pragma unroll
      for (int u = 0; u < 8; ++u) {
        const int rb = wr * 4 + t;
        const int kb2 = u >> 1;
        const int q2 = (u & 1) * 2 + (lr >> 3), j2 = lr & 7;
#pragma unroll
        for (int i = 0; i < 4; ++i) {
          float v = acc[t][u][i] + b1w[u];
          v = v > 0.f ? v : 0.f;
          u32 byteoff = ((u32)(((p * 8 + rb) * 4 + kb2) * 64 + q2 * 16 + q * 4 + i)) * 16 + j2 * 2;
          *(u16*)(smem + byteoff) = f2bf(v);
        }
      }
  }
  __syncthreads();

  // GEMM2 single sweep: wave owns rows wv*32..+31 for BOTH pairs
  f32x4 acc2[2][2][4] = {};
#pragma unroll
  for (int pl = 0; pl < 2; ++pl)
#pragma unroll
    for (int kk = 0; kk < 4; ++kk) {
      short8 a2[2], b2v[4];
#pragma unroll
      for (int t2 = 0; t2 < 2; ++t2)
        a2[t2] = *(const short8*)(smem + (u32)(((pl * 8 + wv * 2 + t2) * 4 + kk)) * 1024 + lane16);
#pragma unroll
      for (int u2 = 0; u2 < 4; ++u2)
        b2v[u2] = *(const short8*)(w2pk + ((u32)(((pr0 + pl) * 4 + kk) * 4 + u2)) * 512 + (u32)lane * 8);
#pragma unroll
      for (int t2 = 0; t2 < 2; ++t2)
#pragma unroll
        for (int u2 = 0; u2 < 4; ++u2)
          acc2[pl][t2][u2] = __builtin_amdgcn_mfma_f32_16x16x32_bf16(a2[t2], b2v[u2], acc2[pl][t2][u2], 0, 0, 0);
    }

  // epilogue: s = sigmoid(relu(h2+b2).W3+b3); out += bw_c * rw * s (atomic)
#pragma unroll
  for (int pl = 0; pl < 2; ++pl) {
    const int pairG = pr0 + pl;
    float bb2[4], bw3v[4];
#pragma unroll
    for (int u2 = 0; u2 < 4; ++u2) {
      bb2[u2]  = eb2[pairG * 64 + u2 * 16 + lr];
      bw3v[u2] = eW3[pairG * 64 + u2 * 16 + lr];
    }
    float b3 = eb3[pairG];
    float bwc = bw[pairG >> 4];
#pragma unroll
    for (int t2 = 0; t2 < 2; ++t2) {
      float pp[4] = {0.f, 0.f, 0.f, 0.f};
#pragma unroll
      for (int u2 = 0; u2 < 4; ++u2)
#pragma unroll
        for (int i = 0; i < 4; ++i) {
          float h = acc2[pl][t2][u2][i] + bb2[u2];
          h = h > 0.f ? h : 0.f;
          pp[i] += h * bw3v[u2];
        }
#pragma unroll
      for (int m = 1; m < 16; m <<= 1)
#pragma unroll
        for (int i = 0; i < 4; ++i) pp[i] += __shfl_xor(pp[i], m, 64);
      if (lr == 0) {
#pragma unroll
        for (int i = 0; i < 4; ++i) {
          int row = wv * 32 + t2 * 16 + q * 4 + i;
          float z = pp[i] + b3;
          float s = 1.f / (1.f + __expf(-z));
          float rw = rwT[(u32)pairG * NB + r0 + row];
          atomicAdd(out + r0 + row, bwc * rw * s);
        }
      }
    }
  }
}

extern "C" void kernel_launch(void* const* d_in, const int* in_sizes, int n_in,
                              void* d_out, int out_size, void* d_ws, size_t ws_size,
                              hipStream_t stream) {
  const float* x     = (const float*)d_in[0];
  const float* rbn_g = (const float*)d_in[1];
  const float* rbn_b = (const float*)d_in[2];
  const float* rbn_m = (const float*)d_in[3];
  const float* rbn_v = (const float*)d_in[4];
  const float* rW1   = (const float*)d_in[5];
  const float* rb1   = (const float*)d_in[6];
  const float* rW2   = (const float*)d_in[7];
  const float* rb2   = (const float*)d_in[8];
  const float* rW3   = (const float*)d_in[9];
  const float* rb3   = (const float*)d_in[10];
  const float* ebn_g = (const float*)d_in[11];
  const float* ebn_b = (const float*)d_in[12];
  const float* ebn_m = (const float*)d_in[13];
  const float* ebn_v = (const float*)d_in[14];
  const float* eW1   = (const float*)d_in[15];
  const float* eb1   = (const float*)d_in[16];
  const float* eW2   = (const float*)d_in[17];
  const float* eb2   = (const float*)d_in[18];
  const float* eW3   = (const float*)d_in[19];
  const float* eb3   = (const float*)d_in[20];
  const float* bw    = (const float*)d_in[21];

  char* ws = (char*)d_ws;
  u16*   xpk   = (u16*)(ws + OFF_XPK);
  u16*   w1pk  = (u16*)(ws + OFF_W1PK);
  u16*   w2pk  = (u16*)(ws + OFF_W2PK);
  u16*   rw1pt = (u16*)(ws + OFF_RW1PT);
  float* pbias = (float*)(ws + OFF_PBIAS);
  float* b1p   = (float*)(ws + OFF_B1P);
  float* rwT   = (float*)(ws + OFF_RWT);
  float* rpb   = (float*)(ws + OFF_RPB);
  float* outf  = (float*)d_out;

  k_prep_all<<<dim3(833), dim3(256), 0, stream>>>(
      x, xpk, ebn_g, ebn_b, ebn_m, ebn_v, eW1, w1pk, pbias, eW2, w2pk,
      rbn_g, rbn_b, rbn_m, rbn_v, rW1, rw1pt, rpb, outf);
  k_router<<<dim3(288), dim3(256), 0, stream>>>(
      xpk, rw1pt, rb1, rpb, rW2, rb2, rW3, rb3, rwT, pbias, eb1, b1p);
  k_expert<<<dim3(1024), dim3(256), 73728, stream>>>(
      xpk, b1p, w2pk, eb2, eW3, eb3, rwT, bw, outf);
}